// Round 11
// baseline (716.424 us; speedup 1.0000x reference)
//
#include <hip/hip_runtime.h>
#include <hip/hip_fp16.h>

#define NNODES 100000
#define NMP 3
#define NEDGES 1000000
#define D 64
#define NTOT (NMP * NNODES)          // 300000
#define BINW 1024                    // nodes per scan bin
#define NBIN 293                     // ceil(NTOT / BINW)
#define NPAD (NBIN * BINW)           // 300032 (padded node arrays)
#define CAPB 10944                   // C slots per bin segment (lambda=10240, +7 sigma)
#define OVCAP 131072                 // overflow entries (12 B each)

typedef __attribute__((ext_vector_type(8))) short bf16x8;
typedef __attribute__((ext_vector_type(4))) float floatx4;

__device__ __forceinline__ unsigned short f2bf(float f) {
    unsigned u = __float_as_uint(f);
    u = (u + 0x7FFFu + ((u >> 16) & 1u)) >> 16;   // RNE
    return (unsigned short)u;
}
__device__ __forceinline__ __half2 u2h(unsigned u) {   // bit-cast u32 -> packed half2
    __half2 r;
    *reinterpret_cast<unsigned*>(&r) = u;
    return r;
}
__device__ __forceinline__ float h2f_lo(unsigned u) {
    return __half2float(__ushort_as_half((unsigned short)(u & 0xFFFFu)));
}
__device__ __forceinline__ float h2f_hi(unsigned u) {
    return __half2float(__ushort_as_half((unsigned short)(u >> 16)));
}

// block-wide exclusive scan via per-wave shfl scan (2 barriers)
__device__ __forceinline__ int block_excl_scan(int v, int t, int nthreads, int* wsums) {
    const int lane = t & 63, wv = t >> 6;
    int s = v;
#pragma unroll
    for (int d = 1; d < 64; d <<= 1) {
        int u = __shfl_up(s, d);
        if (lane >= d) s += u;
    }
    if (lane == 63) wsums[wv] = s;
    __syncthreads();
    if (wv == 0) {
        const int nw = nthreads >> 6;
        int ws = (lane < nw) ? wsums[lane] : 0;
#pragma unroll
        for (int d = 1; d < 8; d <<= 1) {
            int u = __shfl_up(ws, d);
            if (lane >= d) ws += u;
        }
        if (lane < nw) wsums[lane] = ws;          // inclusive wave sums
    }
    __syncthreads();
    int wbase = wv ? wsums[wv - 1] : 0;
    return wbase + s - v;                          // exclusive prefix of v
}

// ---------------- hist: per-node edge count + weighted degree (global atomics, streaming) ------
__global__ __launch_bounds__(256) void hist_kernel(const int* __restrict__ ei,
                                                   const float* __restrict__ ew,
                                                   int* __restrict__ cnt,
                                                   float* __restrict__ wsum) {
    const int mp = blockIdx.y;
    int e = blockIdx.x * 1024 + threadIdx.x;
#pragma unroll
    for (int i = 0; i < 4; ++i, e += 256) {
        if (e < NEDGES) {
            int c = ei[(mp * 2 + 1) * NEDGES + e];
            float w = ew[mp * NEDGES + e];
            int cflat = mp * NNODES + c;
            atomicAdd(&cnt[cflat], 1);
            __hip_atomic_fetch_add(&wsum[cflat], w, __ATOMIC_RELAXED,
                                   __HIP_MEMORY_SCOPE_AGENT);   // native global f32 add
        }
    }
}

// ---------------- scan: bin-local exclusive scan of exact counts -> nodeoff/pcur/dinv ----------
__global__ __launch_bounds__(512) void scan_kernel(const int* __restrict__ cnt,
                                                   const float* __restrict__ wsum,
                                                   int2* __restrict__ nodeoff,
                                                   int* __restrict__ pcur,
                                                   float* __restrict__ dinv) {
    const int bin = blockIdx.x;
    __shared__ int wsums[8];
    const int t = threadIdx.x;
    const int n0 = (bin << 10) + 2 * t, n1 = n0 + 1;
    int c0 = cnt[n0], c1 = cnt[n1];                 // pad nodes: cnt = 0 (memset)
    int ex = block_excl_scan(c0 + c1, t, 512, wsums);
    const int base = bin * CAPB;
    int s0 = base + ex, s1 = s0 + c0;
    nodeoff[n0] = make_int2(s0, c0);
    nodeoff[n1] = make_int2(s1, c1);
    pcur[n0] = s0;
    pcur[n1] = s1;
    float d0 = wsum[n0], d1 = wsum[n1];
    dinv[n0] = (d0 > 0.0f) ? rsqrtf(d0) : 0.0f;
    dinv[n1] = (d1 > 0.0f) ? rsqrtf(d1) : 0.0f;
}

// ---------------- scatter: stream edges -> C[slot] via per-node cursor atomics ----------------
// C writes are scattered 8B but C (25.6 MB) is L2-resident during the pass (r7: staging ~= direct).
__global__ __launch_bounds__(256) void scatter_kernel(const int* __restrict__ ei,
                                                      const float* __restrict__ ew,
                                                      int* __restrict__ pcur,
                                                      int* __restrict__ ovcur,
                                                      int* __restrict__ ovf,
                                                      uint2* __restrict__ C) {
    const int mp = blockIdx.y;
    int e = blockIdx.x * 1024 + threadIdx.x;
#pragma unroll
    for (int i = 0; i < 4; ++i, e += 256) {
        if (e < NEDGES) {
            int r = ei[(mp * 2 + 0) * NEDGES + e];
            int c = ei[(mp * 2 + 1) * NEDGES + e];
            float w = ew[mp * NEDGES + e];
            int cflat = mp * NNODES + c;
            int rflat = mp * NNODES + r;
            int slot = atomicAdd(&pcur[cflat], 1);
            int binlim = ((cflat >> 10) + 1) * CAPB;
            if (slot < binlim) {
                C[slot] = make_uint2((unsigned)rflat, __float_as_uint(w));
            } else {                               // correctness valve (~never: cap is +7 sigma)
                int op = atomicAdd(ovcur, 1);
                if (op < OVCAP) {
                    ovf[3 * op] = cflat;
                    ovf[3 * op + 1] = rflat;
                    ovf[3 * op + 2] = __float_as_int(w);
                }
            }
        }
    }
}

// ---------------- prep: W fp32 [mp][k][n] -> bf16 transposed wT [mp][n][k] ----------------
__global__ __launch_bounds__(256) void prep_w_kernel(const float* __restrict__ W,
                                                     unsigned short* __restrict__ wT) {
    int idx = blockIdx.x * 256 + threadIdx.x;
    if (idx >= NMP * D * D) return;
    int mp = idx >> 12, rem = idx & 4095;
    int k = rem >> 6, n = rem & 63;
    wT[(mp * D + n) * D + k] = f2bf(W[idx]);
}

// ---------------- MFMA GEMM (operand-swapped); h stored as F16, dinv[row] folded --------------
__global__ __launch_bounds__(256) void gemm_kernel(const float* __restrict__ x,
                                                   const unsigned short* __restrict__ wT,
                                                   const float* __restrict__ dinv,
                                                   unsigned short* __restrict__ h) {
    const int wave = threadIdx.x >> 6;
    const int lane = threadIdx.x & 63;
    const int rowbase = (blockIdx.x * 4 + wave) * 16;
    if (rowbase >= NNODES) return;
    const int m = lane & 15;
    const int q = lane >> 4;
    const float4* xr = (const float4*)(x + (size_t)(rowbase + m) * D);
    bf16x8 a[2];
#pragma unroll
    for (int kc = 0; kc < 2; ++kc) {
        float4 x0 = xr[kc * 8 + q * 2];
        float4 x1 = xr[kc * 8 + q * 2 + 1];
        a[kc][0] = f2bf(x0.x); a[kc][1] = f2bf(x0.y);
        a[kc][2] = f2bf(x0.z); a[kc][3] = f2bf(x0.w);
        a[kc][4] = f2bf(x1.x); a[kc][5] = f2bf(x1.y);
        a[kc][6] = f2bf(x1.z); a[kc][7] = f2bf(x1.w);
    }
#pragma unroll
    for (int mp = 0; mp < NMP; ++mp) {
        float dv = dinv[mp * NNODES + rowbase + m];   // per x-row scale
#pragma unroll
        for (int nt = 0; nt < 4; ++nt) {
            const bf16x8* bp = (const bf16x8*)(wT + (size_t)(mp * D + nt * 16 + m) * D);
            bf16x8 b0 = bp[q];       // k = q*8 .. +7
            bf16x8 b1 = bp[4 + q];   // k = 32 + q*8 .. +7
            floatx4 acc = {0.f, 0.f, 0.f, 0.f};
            acc = __builtin_amdgcn_mfma_f32_16x16x32_bf16(b0, a[0], acc, 0, 0, 0);
            acc = __builtin_amdgcn_mfma_f32_16x16x32_bf16(b1, a[1], acc, 0, 0, 0);
            unsigned v0 = (unsigned)__half_as_ushort(__float2half(acc[0] * dv)) |
                          ((unsigned)__half_as_ushort(__float2half(acc[1] * dv)) << 16);
            unsigned v1 = (unsigned)__half_as_ushort(__float2half(acc[2] * dv)) |
                          ((unsigned)__half_as_ushort(__float2half(acc[3] * dv)) << 16);
            *(uint2*)(h + ((size_t)mp * NNODES + rowbase + m) * D + nt * 16 + q * 4) =
                make_uint2(v0, v1);
        }
    }
}

// ---------------- gather: 2 nodes/wave, 4 edge slots/node, depth-2 pipeline, pk_fma_f16 --------
// The measured-optimal config (r6: 70us). 32 lanes/node: g = edge slot, f = feature chunk.
__global__ __launch_bounds__(256) void gather_kernel(const int2* __restrict__ nodeoff,
                                                     const uint2* __restrict__ dense,
                                                     const unsigned short* __restrict__ h,
                                                     const float* __restrict__ dinv,
                                                     const int* __restrict__ ovcur,
                                                     const int* __restrict__ ovf,
                                                     float* __restrict__ out) {
    const int tid = threadIdx.x;
    const int wave = tid >> 6, lane = tid & 63;
    const int sub = lane >> 5;     // node within wave (0..1)
    const int g = (lane >> 3) & 3; // edge slot (0..3)
    const int f = lane & 7;        // feature chunk (8 f16 = 16 B)
    const int w = blockIdx.x * 8 + wave * 2 + sub;   // NTOT = 8*37500
    int2 off = nodeoff[w];
    const int start = off.x, end = off.x + off.y;
    const uint4* hp = (const uint4*)h;               // h at ws offset 0: 128B-row aligned
    __half2 acc2[4];
    acc2[0] = __float2half2_rn(0.0f); acc2[1] = __float2half2_rn(0.0f);
    acc2[2] = __float2half2_rn(0.0f); acc2[3] = __float2half2_rn(0.0f);
    if (end > start) {
        const int last = end - 1;
        uint2 prA = dense[min(start + g, last)];
        uint2 prB = dense[min(start + 4 + g, last)];
        uint4 hvA = hp[(size_t)prA.x * 8 + f];
        for (int p = start; p < end; p += 4) {
            uint2 prC = dense[min(p + 8 + g, last)];
            uint4 hvB = hp[(size_t)prB.x * 8 + f];   // addr ready (record loaded 2 rounds ago)
            float wgt = (p + g < end) ? __uint_as_float(prA.y) : 0.0f;
            __half2 wp = __float2half2_rn(wgt);
            acc2[0] = __hfma2(u2h(hvA.x), wp, acc2[0]);
            acc2[1] = __hfma2(u2h(hvA.y), wp, acc2[1]);
            acc2[2] = __hfma2(u2h(hvA.z), wp, acc2[2]);
            acc2[3] = __hfma2(u2h(hvA.w), wp, acc2[3]);
            prA = prB; hvA = hvB; prB = prC;
        }
    }
    float acc[8];
    acc[0] = __low2float(acc2[0]); acc[1] = __high2float(acc2[0]);
    acc[2] = __low2float(acc2[1]); acc[3] = __high2float(acc2[1]);
    acc[4] = __low2float(acc2[2]); acc[5] = __high2float(acc2[2]);
    acc[6] = __low2float(acc2[3]); acc[7] = __high2float(acc2[3]);
#pragma unroll
    for (int j = 0; j < 8; ++j) {                   // reduce across 4 edge slots (f32)
        acc[j] += __shfl_xor(acc[j], 8);
        acc[j] += __shfl_xor(acc[j], 16);
    }
    float dv = dinv[w];
    if (g < 2) {
        const int ovn = min(*ovcur, OVCAP);          // 0 in practice (cap is +7 sigma)
        if (ovn > 0) {
            for (int i = 0; i < ovn; ++i) {
                if (ovf[3 * i] == w) {
                    float wgt = __int_as_float(ovf[3 * i + 2]);
                    uint4 hv = hp[(size_t)ovf[3 * i + 1] * 8 + f];
                    acc[0] += wgt * h2f_lo(hv.x); acc[1] += wgt * h2f_hi(hv.x);
                    acc[2] += wgt * h2f_lo(hv.y); acc[3] += wgt * h2f_hi(hv.y);
                    acc[4] += wgt * h2f_lo(hv.z); acc[5] += wgt * h2f_hi(hv.z);
                    acc[6] += wgt * h2f_lo(hv.w); acc[7] += wgt * h2f_hi(hv.w);
                }
            }
        }
        float4 o = g ? make_float4(acc[4], acc[5], acc[6], acc[7])
                     : make_float4(acc[0], acc[1], acc[2], acc[3]);
        o.x = fmaxf(o.x * dv, 0.0f);
        o.y = fmaxf(o.y * dv, 0.0f);
        o.z = fmaxf(o.z * dv, 0.0f);
        o.w = fmaxf(o.w * dv, 0.0f);
        ((float4*)out)[(size_t)w * 16 + f * 2 + g] = o;   // 256 B contiguous per node
    }
}

extern "C" void kernel_launch(void* const* d_in, const int* in_sizes, int n_in,
                              void* d_out, int out_size, void* d_ws, size_t ws_size,
                              hipStream_t stream) {
    const float* x  = (const float*)d_in[0];   // [N, 64]
    const float* W  = (const float*)d_in[1];   // [3, 64, 64]
    const int*   ei = (const int*)d_in[2];     // [3, 2, E]
    const float* ew = (const float*)d_in[3];   // [3, E]
    float* out = (float*)d_out;                // [3, N, 64]

    // layout (bytes). No A staging buffer anymore; node arrays padded to NPAD=300032.
    char* ws = (char*)d_ws;
    unsigned short* h  = (unsigned short*)(ws + 0);            // 38,400,000 B (128B-aligned)
    uint2* C           = (uint2*)(ws + 38400000);              // 293*10944*8 = 25,652,736 B
    int2*  nodeoff     = (int2*)(ws + 64052736);               // 2,400,256 B
    float* dinv        = (float*)(ws + 66452992);              // 1,200,128 B
    unsigned short* wT = (unsigned short*)(ws + 67653120);     // 24,576 B
    int*   cnt         = (int*)(ws + 67677696);                // 1,200,128 B  } one memset
    float* wsum        = (float*)(ws + 68877824);              // 1,200,128 B  } (2,400,256 B)
    int*   pcur        = (int*)(ws + 70077952);                // 1,200,128 B
    int*   ovcur       = (int*)(ws + 71278080);                // 4 B
    int*   ovf         = (int*)(ws + 71278084);                // 1,572,864 B -> ends ~72.85 MB

    hipMemsetAsync(cnt, 0, 2400256, stream);   // cnt + wsum (adjacent)
    hipMemsetAsync(ovcur, 0, 4, stream);

    dim3 egrid((NEDGES + 1023) / 1024, NMP);
    hist_kernel<<<egrid, 256, 0, stream>>>(ei, ew, cnt, wsum);
    scan_kernel<<<NBIN, 512, 0, stream>>>(cnt, wsum, nodeoff, pcur, dinv);
    scatter_kernel<<<egrid, 256, 0, stream>>>(ei, ew, pcur, ovcur, ovf, C);
    prep_w_kernel<<<(NMP * D * D + 255) / 256, 256, 0, stream>>>(W, wT);
    gemm_kernel<<<(NNODES / 16 + 3) / 4, 256, 0, stream>>>(x, wT, dinv, h);
    gather_kernel<<<NTOT / 8, 256, 0, stream>>>(nodeoff, C, h, dinv, ovcur, ovf, out);
}

// Round 12
// 289.953 us; speedup vs baseline: 2.4708x; 2.4708x over previous
//
#include <hip/hip_runtime.h>
#include <hip/hip_fp16.h>

#define NNODES 100000
#define NMP 3
#define NEDGES 1000000
#define D 64
#define NTOT (NMP * NNODES)          // 300000
#define BINW 1024                    // destination nodes per bin
#define NBIN 293                     // ceil(NTOT / BINW)
#define CAPB 10944                   // slots per bin segment (lambda=10240, +7 sigma)
#define T1 5632                      // edges per split block (11/thread, LDS-staged)
#define RPT 11                       // records per thread
#define OVCAP 131072                 // overflow entries (12 B each)

typedef __attribute__((ext_vector_type(8))) short bf16x8;
typedef __attribute__((ext_vector_type(4))) float floatx4;

__device__ __forceinline__ unsigned short f2bf(float f) {
    unsigned u = __float_as_uint(f);
    u = (u + 0x7FFFu + ((u >> 16) & 1u)) >> 16;   // RNE
    return (unsigned short)u;
}
__device__ __forceinline__ __half2 u2h(unsigned u) {   // bit-cast u32 -> packed half2
    __half2 r;
    *reinterpret_cast<unsigned*>(&r) = u;
    return r;
}

// ---------------- split: multisplit into 293 bins, LDS-staged coalesced scatter ----------------
// NOTE (r11): never per-element device-scope global atomics on MI355X -- they bypass the
// non-coherent per-XCD L2s (~64B line per atomic to the coherence point). LDS-reduce first.
__global__ __launch_bounds__(512) void split_kernel(const int* __restrict__ ei,
                                                    const float* __restrict__ ew,
                                                    int* __restrict__ gcur,
                                                    int* __restrict__ ovcur,
                                                    int* __restrict__ ovf,
                                                    uint2* __restrict__ A) {
    __shared__ uint2 stage[T1];
    __shared__ unsigned short sbin[T1];
    __shared__ int hist[NBIN], lbase[NBIN], gbase[NBIN], lcur[NBIN];
    __shared__ int sh[512];
    const int t = threadIdx.x;
    const int mp = blockIdx.y;
    const int e0 = blockIdx.x * T1;
    const int nrec = min(T1, NEDGES - e0);
    for (int i = t; i < NBIN; i += 512) hist[i] = 0;
    __syncthreads();
    unsigned key[RPT]; float w[RPT]; int bn[RPT];
#pragma unroll
    for (int i = 0; i < RPT; ++i) {
        int e = e0 + i * 512 + t;
        bn[i] = -1;
        if (e < NEDGES) {
            int r = ei[(mp * 2 + 0) * NEDGES + e];
            int c = ei[(mp * 2 + 1) * NEDGES + e];
            w[i] = ew[mp * NEDGES + e];
            int cflat = mp * NNODES + c;
            int rflat = mp * NNODES + r;
            int b = cflat >> 10;
            bn[i] = b;
            key[i] = ((unsigned)(cflat & 1023) << 19) | (unsigned)rflat;
            atomicAdd(&hist[b], 1);
        }
    }
    __syncthreads();
    int v = (t < NBIN) ? hist[t] : 0;
    sh[t] = v;
    __syncthreads();
    for (int d = 1; d < 512; d <<= 1) {
        int add = (t >= d) ? sh[t - d] : 0;
        __syncthreads();
        sh[t] += add;
        __syncthreads();
    }
    if (t < NBIN) {
        int ex = sh[t] - v;
        lbase[t] = ex;
        lcur[t] = ex;
        gbase[t] = v ? atomicAdd(&gcur[t], v) : 0;
    }
    __syncthreads();
#pragma unroll
    for (int i = 0; i < RPT; ++i) {
        if (bn[i] >= 0) {
            int s = atomicAdd(&lcur[bn[i]], 1);
            stage[s] = make_uint2(key[i], __float_as_uint(w[i]));
            sbin[s] = (unsigned short)bn[i];
        }
    }
    __syncthreads();
    for (int s = t; s < nrec; s += 512) {
        int b = sbin[s];
        uint2 rec = stage[s];
        int pos = gbase[b] + (s - lbase[b]);
        if (pos < CAPB) {
            A[(size_t)b * CAPB + pos] = rec;
        } else {                                   // correctness valve (~never)
            int op = atomicAdd(ovcur, 1);
            if (op < OVCAP) {
                int cflat = (b << 10) | (int)(rec.x >> 19);
                ovf[3 * op] = cflat;
                ovf[3 * op + 1] = (int)(rec.x & 0x7FFFFu);
                ovf[3 * op + 2] = (int)rec.y;
            }
        }
    }
}

// ---------------- compact2: per 1024-node bin -> per-node CSR {rflat, ew}; dinv ----------------
__global__ __launch_bounds__(256) void compact2_kernel(const int* __restrict__ gcur,
                                                       const uint2* __restrict__ A,
                                                       const int* __restrict__ ovcur,
                                                       const int* __restrict__ ovf,
                                                       uint2* __restrict__ C,
                                                       int2* __restrict__ nodeoff,
                                                       float* __restrict__ dinv) {
    const int bin = blockIdx.x;
    __shared__ int cnt[BINW];
    __shared__ float wsum[BINW];
    __shared__ int pos[BINW];
    __shared__ int sh[256];
    const int t = threadIdx.x;
    for (int i = t; i < BINW; i += 256) { cnt[i] = 0; wsum[i] = 0.0f; }
    __syncthreads();
    const int len = min(gcur[bin], CAPB);
    const uint2* Ab = A + (size_t)bin * CAPB;
    for (int p = t; p < len; p += 256) {
        uint2 rec = Ab[p];
        atomicAdd(&cnt[rec.x >> 19], 1);
        atomicAdd(&wsum[rec.x >> 19], __uint_as_float(rec.y));
    }
    const int ovn = min(*ovcur, OVCAP);
    for (int i = t; i < ovn; i += 256) {
        int cflat = ovf[3 * i];
        if ((cflat >> 10) == bin) {
            atomicAdd(&cnt[cflat & 1023], 1);
            atomicAdd(&wsum[cflat & 1023], __int_as_float(ovf[3 * i + 2]));
        }
    }
    __syncthreads();
    // scan: thread t owns nodes 4t..4t+3
    int c0 = cnt[4 * t], c1 = cnt[4 * t + 1], c2 = cnt[4 * t + 2], c3 = cnt[4 * t + 3];
    int vsum = c0 + c1 + c2 + c3;
    sh[t] = vsum;
    __syncthreads();
    for (int d = 1; d < 256; d <<= 1) {
        int add = (t >= d) ? sh[t - d] : 0;
        __syncthreads();
        sh[t] += add;
        __syncthreads();
    }
    const int base = bin * CAPB;
    const int lim = base + CAPB;
    int p0 = base + sh[t] - vsum;
    int p1 = p0 + c0, p2 = p1 + c1, p3 = p2 + c2;
    pos[4 * t] = p0; pos[4 * t + 1] = p1; pos[4 * t + 2] = p2; pos[4 * t + 3] = p3;
    int starts[4] = {p0, p1, p2, p3};
    int cs[4] = {c0, c1, c2, c3};
#pragma unroll
    for (int j = 0; j < 4; ++j) {
        int cl = 4 * t + j;
        int node = (bin << 10) + cl;
        if (node < NTOT) {
            nodeoff[node] = make_int2(starts[j], cs[j]);
            float dg = wsum[cl];
            dinv[node] = (dg > 0.0f) ? rsqrtf(dg) : 0.0f;
        }
    }
    __syncthreads();
    for (int p = t; p < len; p += 256) {
        uint2 rec = Ab[p];
        int s = atomicAdd(&pos[rec.x >> 19], 1);
        if (s < lim) C[s] = make_uint2(rec.x & 0x7FFFFu, rec.y);
    }
    for (int i = t; i < ovn; i += 256) {
        int cflat = ovf[3 * i];
        if ((cflat >> 10) == bin) {
            int s = atomicAdd(&pos[cflat & 1023], 1);
            if (s < lim) C[s] = make_uint2((unsigned)ovf[3 * i + 1], (unsigned)ovf[3 * i + 2]);
        }
    }
}

// ---------------- prep: W fp32 [mp][k][n] -> bf16 transposed wT [mp][n][k] ----------------
__global__ __launch_bounds__(256) void prep_w_kernel(const float* __restrict__ W,
                                                     unsigned short* __restrict__ wT) {
    int idx = blockIdx.x * 256 + threadIdx.x;
    if (idx >= NMP * D * D) return;
    int mp = idx >> 12, rem = idx & 4095;
    int k = rem >> 6, n = rem & 63;
    wT[(mp * D + n) * D + k] = f2bf(W[idx]);
}

// ---------------- MFMA GEMM (operand-swapped); h stored as F16, dinv[row] folded --------------
__global__ __launch_bounds__(256) void gemm_kernel(const float* __restrict__ x,
                                                   const unsigned short* __restrict__ wT,
                                                   const float* __restrict__ dinv,
                                                   unsigned short* __restrict__ h) {
    const int wave = threadIdx.x >> 6;
    const int lane = threadIdx.x & 63;
    const int rowbase = (blockIdx.x * 4 + wave) * 16;
    if (rowbase >= NNODES) return;
    const int m = lane & 15;
    const int q = lane >> 4;
    const float4* xr = (const float4*)(x + (size_t)(rowbase + m) * D);
    bf16x8 a[2];
#pragma unroll
    for (int kc = 0; kc < 2; ++kc) {
        float4 x0 = xr[kc * 8 + q * 2];
        float4 x1 = xr[kc * 8 + q * 2 + 1];
        a[kc][0] = f2bf(x0.x); a[kc][1] = f2bf(x0.y);
        a[kc][2] = f2bf(x0.z); a[kc][3] = f2bf(x0.w);
        a[kc][4] = f2bf(x1.x); a[kc][5] = f2bf(x1.y);
        a[kc][6] = f2bf(x1.z); a[kc][7] = f2bf(x1.w);
    }
#pragma unroll
    for (int mp = 0; mp < NMP; ++mp) {
        float dv = dinv[mp * NNODES + rowbase + m];   // per x-row scale
#pragma unroll
        for (int nt = 0; nt < 4; ++nt) {
            const bf16x8* bp = (const bf16x8*)(wT + (size_t)(mp * D + nt * 16 + m) * D);
            bf16x8 b0 = bp[q];       // k = q*8 .. +7
            bf16x8 b1 = bp[4 + q];   // k = 32 + q*8 .. +7
            floatx4 acc = {0.f, 0.f, 0.f, 0.f};
            acc = __builtin_amdgcn_mfma_f32_16x16x32_bf16(b0, a[0], acc, 0, 0, 0);
            acc = __builtin_amdgcn_mfma_f32_16x16x32_bf16(b1, a[1], acc, 0, 0, 0);
            unsigned v0 = (unsigned)__half_as_ushort(__float2half(acc[0] * dv)) |
                          ((unsigned)__half_as_ushort(__float2half(acc[1] * dv)) << 16);
            unsigned v1 = (unsigned)__half_as_ushort(__float2half(acc[2] * dv)) |
                          ((unsigned)__half_as_ushort(__float2half(acc[3] * dv)) << 16);
            *(uint2*)(h + ((size_t)mp * NNODES + rowbase + m) * D + nt * 16 + q * 4) =
                make_uint2(v0, v1);
        }
    }
}

// ---------------- gather: 2 nodes/wave, 4 edge slots/node, depth-2 pipeline, pk_fma_f16 --------
// Launched as TWO half-grid dispatches (base = 0, NTOT/2) so each half ~35us: lets the
// harness's top-5 surface the second-longest kernel (observability, not perf).
__global__ __launch_bounds__(256) void gather_kernel(const int2* __restrict__ nodeoff,
                                                     const uint2* __restrict__ dense,
                                                     const unsigned short* __restrict__ h,
                                                     const float* __restrict__ dinv,
                                                     float* __restrict__ out,
                                                     int base) {
    const int tid = threadIdx.x;
    const int wave = tid >> 6, lane = tid & 63;
    const int sub = lane >> 5;     // node within wave (0..1)
    const int g = (lane >> 3) & 3; // edge slot (0..3)
    const int f = lane & 7;        // feature chunk (8 f16 = 16 B)
    const int w = base + blockIdx.x * 8 + wave * 2 + sub;
    int2 off = nodeoff[w];
    const int start = off.x, end = off.x + off.y;
    const uint4* hp = (const uint4*)h;               // h at ws offset 0: 128B-row aligned
    __half2 acc2[4];
    acc2[0] = __float2half2_rn(0.0f); acc2[1] = __float2half2_rn(0.0f);
    acc2[2] = __float2half2_rn(0.0f); acc2[3] = __float2half2_rn(0.0f);
    if (end > start) {
        const int last = end - 1;
        uint2 prA = dense[min(start + g, last)];
        uint2 prB = dense[min(start + 4 + g, last)];
        uint4 hvA = hp[(size_t)prA.x * 8 + f];
        for (int p = start; p < end; p += 4) {
            uint2 prC = dense[min(p + 8 + g, last)];
            uint4 hvB = hp[(size_t)prB.x * 8 + f];   // addr ready (record loaded 2 rounds ago)
            float wgt = (p + g < end) ? __uint_as_float(prA.y) : 0.0f;
            __half2 wp = __float2half2_rn(wgt);
            acc2[0] = __hfma2(u2h(hvA.x), wp, acc2[0]);
            acc2[1] = __hfma2(u2h(hvA.y), wp, acc2[1]);
            acc2[2] = __hfma2(u2h(hvA.z), wp, acc2[2]);
            acc2[3] = __hfma2(u2h(hvA.w), wp, acc2[3]);
            prA = prB; hvA = hvB; prB = prC;
        }
    }
    float acc[8];
    acc[0] = __low2float(acc2[0]); acc[1] = __high2float(acc2[0]);
    acc[2] = __low2float(acc2[1]); acc[3] = __high2float(acc2[1]);
    acc[4] = __low2float(acc2[2]); acc[5] = __high2float(acc2[2]);
    acc[6] = __low2float(acc2[3]); acc[7] = __high2float(acc2[3]);
#pragma unroll
    for (int j = 0; j < 8; ++j) {                   // reduce across 4 edge slots (f32)
        acc[j] += __shfl_xor(acc[j], 8);
        acc[j] += __shfl_xor(acc[j], 16);
    }
    float dv = dinv[w];
    if (g < 2) {
        float4 o = g ? make_float4(acc[4], acc[5], acc[6], acc[7])
                     : make_float4(acc[0], acc[1], acc[2], acc[3]);
        o.x = fmaxf(o.x * dv, 0.0f);
        o.y = fmaxf(o.y * dv, 0.0f);
        o.z = fmaxf(o.z * dv, 0.0f);
        o.w = fmaxf(o.w * dv, 0.0f);
        ((float4*)out)[(size_t)w * 16 + f * 2 + g] = o;   // 256 B contiguous per node
    }
}

extern "C" void kernel_launch(void* const* d_in, const int* in_sizes, int n_in,
                              void* d_out, int out_size, void* d_ws, size_t ws_size,
                              hipStream_t stream) {
    const float* x  = (const float*)d_in[0];   // [N, 64]
    const float* W  = (const float*)d_in[1];   // [3, 64, 64]
    const int*   ei = (const int*)d_in[2];     // [3, 2, E]
    const float* ew = (const float*)d_in[3];   // [3, E]
    float* out = (float*)d_out;                // [3, N, 64]

    // layout (bytes). A (25.65 MB) is dead after compact2; h (38.4 MB) overlays it.
    // NOTE: keep randomly-read buffers (h) 128B-aligned -- round-5's mod-64=24 xb cost +50% fetch.
    char* ws = (char*)d_ws;
    uint2* A           = (uint2*)(ws + 0);                     // 293*10944*8 = 25,652,736 B
    unsigned short* h  = (unsigned short*)(ws + 0);            // 38,400,000 B (overlays A)
    uint2* C           = (uint2*)(ws + 38400000);              // 25,652,736 B
    int2*  nodeoff     = (int2*)(ws + 64052736);               // 2,400,000 B
    float* dinv        = (float*)(ws + 66452736);              // 1,200,000 B
    unsigned short* wT = (unsigned short*)(ws + 67652736);     // 24,576 B
    int*   gcur        = (int*)(ws + 67677312);                // 1,172 B
    int*   ovcur       = (int*)(ws + 67678484);                // 4 B (adjacent to gcur)
    int*   ovf         = (int*)(ws + 67678488);                // 1,572,864 B -> ends ~69.25 MB

    hipMemsetAsync(gcur, 0, 1176, stream);     // gcur + ovcur

    split_kernel<<<dim3((NEDGES + T1 - 1) / T1, NMP), 512, 0, stream>>>(ei, ew, gcur,
                                                                        ovcur, ovf, A);
    compact2_kernel<<<NBIN, 256, 0, stream>>>(gcur, A, ovcur, ovf, C, nodeoff, dinv);
    prep_w_kernel<<<(NMP * D * D + 255) / 256, 256, 0, stream>>>(W, wT);
    gemm_kernel<<<(NNODES / 16 + 3) / 4, 256, 0, stream>>>(x, wT, dinv, h);
    gather_kernel<<<NTOT / 16, 256, 0, stream>>>(nodeoff, C, h, dinv, out, 0);
    gather_kernel<<<NTOT / 16, 256, 0, stream>>>(nodeoff, C, h, dinv, out, NTOT / 2);
}

// Round 13
// 284.253 us; speedup vs baseline: 2.5204x; 1.0201x over previous
//
#include <hip/hip_runtime.h>
#include <hip/hip_fp16.h>

#define NNODES 100000
#define NMP 3
#define NEDGES 1000000
#define D 64
#define NTOT (NMP * NNODES)          // 300000
#define BINW 1024                    // destination nodes per bin
#define NBIN 293                     // ceil(NTOT / BINW)
#define CAPB 10944                   // slots per bin segment (lambda=10240, +7 sigma)
#define T1 5632                      // edges per split block (11/thread, LDS-staged)
#define RPT 11                       // records per thread
#define OVCAP 131072                 // overflow entries (12 B each)

typedef __attribute__((ext_vector_type(8))) short bf16x8;
typedef __attribute__((ext_vector_type(4))) float floatx4;

__device__ __forceinline__ unsigned short f2bf(float f) {
    unsigned u = __float_as_uint(f);
    u = (u + 0x7FFFu + ((u >> 16) & 1u)) >> 16;   // RNE
    return (unsigned short)u;
}
__device__ __forceinline__ __half2 u2h(unsigned u) {   // bit-cast u32 -> packed half2
    __half2 r;
    *reinterpret_cast<unsigned*>(&r) = u;
    return r;
}

// ---------------- split: multisplit into 293 bins, LDS-staged coalesced scatter ----------------
// NOTE (r11): never per-element device-scope global atomics on MI355X -- they bypass the
// non-coherent per-XCD L2s (~64B line per atomic to the coherence point). LDS-reduce first.
__global__ __launch_bounds__(512) void split_kernel(const int* __restrict__ ei,
                                                    const float* __restrict__ ew,
                                                    int* __restrict__ gcur,
                                                    int* __restrict__ ovcur,
                                                    int* __restrict__ ovf,
                                                    uint2* __restrict__ A) {
    __shared__ uint2 stage[T1];
    __shared__ unsigned short sbin[T1];
    __shared__ int hist[NBIN], lbase[NBIN], gbase[NBIN], lcur[NBIN];
    __shared__ int sh[512];
    const int t = threadIdx.x;
    const int mp = blockIdx.y;
    const int e0 = blockIdx.x * T1;
    const int nrec = min(T1, NEDGES - e0);
    for (int i = t; i < NBIN; i += 512) hist[i] = 0;
    __syncthreads();
    unsigned key[RPT]; float w[RPT]; int bn[RPT];
#pragma unroll
    for (int i = 0; i < RPT; ++i) {
        int e = e0 + i * 512 + t;
        bn[i] = -1;
        if (e < NEDGES) {
            int r = ei[(mp * 2 + 0) * NEDGES + e];
            int c = ei[(mp * 2 + 1) * NEDGES + e];
            w[i] = ew[mp * NEDGES + e];
            int cflat = mp * NNODES + c;
            int rflat = mp * NNODES + r;
            int b = cflat >> 10;
            bn[i] = b;
            key[i] = ((unsigned)(cflat & 1023) << 19) | (unsigned)rflat;
            atomicAdd(&hist[b], 1);
        }
    }
    __syncthreads();
    int v = (t < NBIN) ? hist[t] : 0;
    sh[t] = v;
    __syncthreads();
    for (int d = 1; d < 512; d <<= 1) {
        int add = (t >= d) ? sh[t - d] : 0;
        __syncthreads();
        sh[t] += add;
        __syncthreads();
    }
    if (t < NBIN) {
        int ex = sh[t] - v;
        lbase[t] = ex;
        lcur[t] = ex;
        gbase[t] = v ? atomicAdd(&gcur[t], v) : 0;
    }
    __syncthreads();
#pragma unroll
    for (int i = 0; i < RPT; ++i) {
        if (bn[i] >= 0) {
            int s = atomicAdd(&lcur[bn[i]], 1);
            stage[s] = make_uint2(key[i], __float_as_uint(w[i]));
            sbin[s] = (unsigned short)bn[i];
        }
    }
    __syncthreads();
    for (int s = t; s < nrec; s += 512) {
        int b = sbin[s];
        uint2 rec = stage[s];
        int pos = gbase[b] + (s - lbase[b]);
        if (pos < CAPB) {
            A[(size_t)b * CAPB + pos] = rec;
        } else {                                   // correctness valve (~never)
            int op = atomicAdd(ovcur, 1);
            if (op < OVCAP) {
                int cflat = (b << 10) | (int)(rec.x >> 19);
                ovf[3 * op] = cflat;
                ovf[3 * op + 1] = (int)(rec.x & 0x7FFFFu);
                ovf[3 * op + 2] = (int)rec.y;
            }
        }
    }
}

// ---------------- compact2: per-bin CSR build, 1024 threads (r12: was 59us at 8.7% occupancy) --
// 16 waves/block hide the LDS-atomic chains; A-sweeps take 10 strided iters (was 40);
// shfl scan (2 barriers) replaces 18-barrier Hillis-Steele; thread t owns node t exactly.
__global__ __launch_bounds__(1024) void compact2_kernel(const int* __restrict__ gcur,
                                                        const uint2* __restrict__ A,
                                                        const int* __restrict__ ovcur,
                                                        const int* __restrict__ ovf,
                                                        uint2* __restrict__ C,
                                                        int2* __restrict__ nodeoff,
                                                        float* __restrict__ dinv) {
    const int bin = blockIdx.x;
    __shared__ int cnt[BINW];
    __shared__ float wsum[BINW];
    __shared__ int pos[BINW];
    __shared__ int wsums[16];
    const int t = threadIdx.x;
    cnt[t] = 0; wsum[t] = 0.0f;
    __syncthreads();
    const int len = min(gcur[bin], CAPB);
    const uint2* Ab = A + (size_t)bin * CAPB;
    for (int p = t; p < len; p += 1024) {
        uint2 rec = Ab[p];
        atomicAdd(&cnt[rec.x >> 19], 1);
        atomicAdd(&wsum[rec.x >> 19], __uint_as_float(rec.y));
    }
    const int ovn = min(*ovcur, OVCAP);
    for (int i = t; i < ovn; i += 1024) {
        int cflat = ovf[3 * i];
        if ((cflat >> 10) == bin) {
            atomicAdd(&cnt[cflat & 1023], 1);
            atomicAdd(&wsum[cflat & 1023], __int_as_float(ovf[3 * i + 2]));
        }
    }
    __syncthreads();
    // exclusive scan over the 1024 node counts: per-wave shfl scan + 16 wave sums
    const int lane = t & 63, wv = t >> 6;
    int c0 = cnt[t];
    int s = c0;
#pragma unroll
    for (int d = 1; d < 64; d <<= 1) {
        int u = __shfl_up(s, d);
        if (lane >= d) s += u;
    }
    if (lane == 63) wsums[wv] = s;
    __syncthreads();
    if (wv == 0) {
        int ws = (lane < 16) ? wsums[lane] : 0;
#pragma unroll
        for (int d = 1; d < 16; d <<= 1) {
            int u = __shfl_up(ws, d);
            if (lane >= d) ws += u;
        }
        if (lane < 16) wsums[lane] = ws;           // inclusive wave sums
    }
    __syncthreads();
    const int base = bin * CAPB;
    const int lim = base + CAPB;
    int p0 = base + (wv ? wsums[wv - 1] : 0) + s - c0;
    pos[t] = p0;
    const int node = (bin << 10) + t;
    if (node < NTOT) {
        nodeoff[node] = make_int2(p0, c0);
        float dg = wsum[t];
        dinv[node] = (dg > 0.0f) ? rsqrtf(dg) : 0.0f;
    }
    __syncthreads();
    for (int p = t; p < len; p += 1024) {
        uint2 rec = Ab[p];
        int sl = atomicAdd(&pos[rec.x >> 19], 1);
        if (sl < lim) C[sl] = make_uint2(rec.x & 0x7FFFFu, rec.y);
    }
    for (int i = t; i < ovn; i += 1024) {
        int cflat = ovf[3 * i];
        if ((cflat >> 10) == bin) {
            int sl = atomicAdd(&pos[cflat & 1023], 1);
            if (sl < lim) C[sl] = make_uint2((unsigned)ovf[3 * i + 1], (unsigned)ovf[3 * i + 2]);
        }
    }
}

// ---------------- prep: W fp32 [mp][k][n] -> bf16 transposed wT [mp][n][k] ----------------
__global__ __launch_bounds__(256) void prep_w_kernel(const float* __restrict__ W,
                                                     unsigned short* __restrict__ wT) {
    int idx = blockIdx.x * 256 + threadIdx.x;
    if (idx >= NMP * D * D) return;
    int mp = idx >> 12, rem = idx & 4095;
    int k = rem >> 6, n = rem & 63;
    wT[(mp * D + n) * D + k] = f2bf(W[idx]);
}

// ---------------- MFMA GEMM (operand-swapped); h stored as F16, dinv[row] folded --------------
__global__ __launch_bounds__(256) void gemm_kernel(const float* __restrict__ x,
                                                   const unsigned short* __restrict__ wT,
                                                   const float* __restrict__ dinv,
                                                   unsigned short* __restrict__ h) {
    const int wave = threadIdx.x >> 6;
    const int lane = threadIdx.x & 63;
    const int rowbase = (blockIdx.x * 4 + wave) * 16;
    if (rowbase >= NNODES) return;
    const int m = lane & 15;
    const int q = lane >> 4;
    const float4* xr = (const float4*)(x + (size_t)(rowbase + m) * D);
    bf16x8 a[2];
#pragma unroll
    for (int kc = 0; kc < 2; ++kc) {
        float4 x0 = xr[kc * 8 + q * 2];
        float4 x1 = xr[kc * 8 + q * 2 + 1];
        a[kc][0] = f2bf(x0.x); a[kc][1] = f2bf(x0.y);
        a[kc][2] = f2bf(x0.z); a[kc][3] = f2bf(x0.w);
        a[kc][4] = f2bf(x1.x); a[kc][5] = f2bf(x1.y);
        a[kc][6] = f2bf(x1.z); a[kc][7] = f2bf(x1.w);
    }
#pragma unroll
    for (int mp = 0; mp < NMP; ++mp) {
        float dv = dinv[mp * NNODES + rowbase + m];   // per x-row scale
#pragma unroll
        for (int nt = 0; nt < 4; ++nt) {
            const bf16x8* bp = (const bf16x8*)(wT + (size_t)(mp * D + nt * 16 + m) * D);
            bf16x8 b0 = bp[q];       // k = q*8 .. +7
            bf16x8 b1 = bp[4 + q];   // k = 32 + q*8 .. +7
            floatx4 acc = {0.f, 0.f, 0.f, 0.f};
            acc = __builtin_amdgcn_mfma_f32_16x16x32_bf16(b0, a[0], acc, 0, 0, 0);
            acc = __builtin_amdgcn_mfma_f32_16x16x32_bf16(b1, a[1], acc, 0, 0, 0);
            unsigned v0 = (unsigned)__half_as_ushort(__float2half(acc[0] * dv)) |
                          ((unsigned)__half_as_ushort(__float2half(acc[1] * dv)) << 16);
            unsigned v1 = (unsigned)__half_as_ushort(__float2half(acc[2] * dv)) |
                          ((unsigned)__half_as_ushort(__float2half(acc[3] * dv)) << 16);
            *(uint2*)(h + ((size_t)mp * NNODES + rowbase + m) * D + nt * 16 + q * 4) =
                make_uint2(v0, v1);
        }
    }
}

// ---------------- gather: 2 nodes/wave, 4 edge slots/node, depth-2 pipeline, pk_fma_f16 --------
// Launched as TWO half-grid dispatches (base = 0, NTOT/2) so each half ~35us: lets the
// harness's top-5 surface the second-longest kernel (observability, not perf).
__global__ __launch_bounds__(256) void gather_kernel(const int2* __restrict__ nodeoff,
                                                     const uint2* __restrict__ dense,
                                                     const unsigned short* __restrict__ h,
                                                     const float* __restrict__ dinv,
                                                     float* __restrict__ out,
                                                     int base) {
    const int tid = threadIdx.x;
    const int wave = tid >> 6, lane = tid & 63;
    const int sub = lane >> 5;     // node within wave (0..1)
    const int g = (lane >> 3) & 3; // edge slot (0..3)
    const int f = lane & 7;        // feature chunk (8 f16 = 16 B)
    const int w = base + blockIdx.x * 8 + wave * 2 + sub;
    int2 off = nodeoff[w];
    const int start = off.x, end = off.x + off.y;
    const uint4* hp = (const uint4*)h;               // h at ws offset 0: 128B-row aligned
    __half2 acc2[4];
    acc2[0] = __float2half2_rn(0.0f); acc2[1] = __float2half2_rn(0.0f);
    acc2[2] = __float2half2_rn(0.0f); acc2[3] = __float2half2_rn(0.0f);
    if (end > start) {
        const int last = end - 1;
        uint2 prA = dense[min(start + g, last)];
        uint2 prB = dense[min(start + 4 + g, last)];
        uint4 hvA = hp[(size_t)prA.x * 8 + f];
        for (int p = start; p < end; p += 4) {
            uint2 prC = dense[min(p + 8 + g, last)];
            uint4 hvB = hp[(size_t)prB.x * 8 + f];   // addr ready (record loaded 2 rounds ago)
            float wgt = (p + g < end) ? __uint_as_float(prA.y) : 0.0f;
            __half2 wp = __float2half2_rn(wgt);
            acc2[0] = __hfma2(u2h(hvA.x), wp, acc2[0]);
            acc2[1] = __hfma2(u2h(hvA.y), wp, acc2[1]);
            acc2[2] = __hfma2(u2h(hvA.z), wp, acc2[2]);
            acc2[3] = __hfma2(u2h(hvA.w), wp, acc2[3]);
            prA = prB; hvA = hvB; prB = prC;
        }
    }
    float acc[8];
    acc[0] = __low2float(acc2[0]); acc[1] = __high2float(acc2[0]);
    acc[2] = __low2float(acc2[1]); acc[3] = __high2float(acc2[1]);
    acc[4] = __low2float(acc2[2]); acc[5] = __high2float(acc2[2]);
    acc[6] = __low2float(acc2[3]); acc[7] = __high2float(acc2[3]);
#pragma unroll
    for (int j = 0; j < 8; ++j) {                   // reduce across 4 edge slots (f32)
        acc[j] += __shfl_xor(acc[j], 8);
        acc[j] += __shfl_xor(acc[j], 16);
    }
    float dv = dinv[w];
    if (g < 2) {
        float4 o = g ? make_float4(acc[4], acc[5], acc[6], acc[7])
                     : make_float4(acc[0], acc[1], acc[2], acc[3]);
        o.x = fmaxf(o.x * dv, 0.0f);
        o.y = fmaxf(o.y * dv, 0.0f);
        o.z = fmaxf(o.z * dv, 0.0f);
        o.w = fmaxf(o.w * dv, 0.0f);
        ((float4*)out)[(size_t)w * 16 + f * 2 + g] = o;   // 256 B contiguous per node
    }
}

extern "C" void kernel_launch(void* const* d_in, const int* in_sizes, int n_in,
                              void* d_out, int out_size, void* d_ws, size_t ws_size,
                              hipStream_t stream) {
    const float* x  = (const float*)d_in[0];   // [N, 64]
    const float* W  = (const float*)d_in[1];   // [3, 64, 64]
    const int*   ei = (const int*)d_in[2];     // [3, 2, E]
    const float* ew = (const float*)d_in[3];   // [3, E]
    float* out = (float*)d_out;                // [3, N, 64]

    // layout (bytes). A (25.65 MB) is dead after compact2; h (38.4 MB) overlays it.
    // NOTE: keep randomly-read buffers (h) 128B-aligned -- round-5's mod-64=24 xb cost +50% fetch.
    char* ws = (char*)d_ws;
    uint2* A           = (uint2*)(ws + 0);                     // 293*10944*8 = 25,652,736 B
    unsigned short* h  = (unsigned short*)(ws + 0);            // 38,400,000 B (overlays A)
    uint2* C           = (uint2*)(ws + 38400000);              // 25,652,736 B
    int2*  nodeoff     = (int2*)(ws + 64052736);               // 2,400,000 B
    float* dinv        = (float*)(ws + 66452736);              // 1,200,000 B
    unsigned short* wT = (unsigned short*)(ws + 67652736);     // 24,576 B
    int*   gcur        = (int*)(ws + 67677312);                // 1,172 B
    int*   ovcur       = (int*)(ws + 67678484);                // 4 B (adjacent to gcur)
    int*   ovf         = (int*)(ws + 67678488);                // 1,572,864 B -> ends ~69.25 MB

    hipMemsetAsync(gcur, 0, 1176, stream);     // gcur + ovcur

    split_kernel<<<dim3((NEDGES + T1 - 1) / T1, NMP), 512, 0, stream>>>(ei, ew, gcur,
                                                                        ovcur, ovf, A);
    compact2_kernel<<<NBIN, 1024, 0, stream>>>(gcur, A, ovcur, ovf, C, nodeoff, dinv);
    prep_w_kernel<<<(NMP * D * D + 255) / 256, 256, 0, stream>>>(W, wT);
    gemm_kernel<<<(NNODES / 16 + 3) / 4, 256, 0, stream>>>(x, wT, dinv, h);
    gather_kernel<<<NTOT / 16, 256, 0, stream>>>(nodeoff, C, h, dinv, out, 0);
    gather_kernel<<<NTOT / 16, 256, 0, stream>>>(nodeoff, C, h, dinv, out, NTOT / 2);
}